// Round 1
// baseline (50.654 us; speedup 1.0000x reference)
//
#include <hip/hip_runtime.h>

// BSplineWarp: out[n,y,x,c] = coords[n,y,x,c] + deltas[n,c,y,x]
// deltas = 3-tap blur([1/6,4/6,1/6], replicate) o bicubic_upsample(32->1024) of disp.
// Combined per-axis filter: <=5 taps on the 32-point coarse grid.

#define A_COEF (-0.75f)

__device__ __forceinline__ float wnear(float d) {
    return ((A_COEF + 2.0f) * d - (A_COEF + 3.0f)) * d * d + 1.0f;
}
__device__ __forceinline__ float wfar(float d) {
    return A_COEF * (((d - 5.0f) * d + 8.0f) * d - 4.0f);
}

// Combined blur+bicubic weights for output coordinate q in [0,1024), in-size 32.
// Produces w[0..4] for (unclamped) coarse taps s..s+4; reader clamps tap to [0,31].
__device__ __forceinline__ void combined_weights(int q, float* w, int* s_out) {
    float acc[5] = {0.f, 0.f, 0.f, 0.f, 0.f};
    const float inv32 = 1.0f / 32.0f;

    int ym = max(q - 1, 0);
    float posm = ((float)ym + 0.5f) * inv32 - 0.5f;
    int i0min = (int)floorf(posm);
    int s = i0min - 1;

#pragma unroll
    for (int dy = -1; dy <= 1; ++dy) {
        float b = (dy == 0) ? (2.0f / 3.0f) : (1.0f / 6.0f);
        int yp = min(max(q + dy, 0), 1023);
        float pos = ((float)yp + 0.5f) * inv32 - 0.5f;
        float fi = floorf(pos);
        int i0 = (int)fi;
        float t = pos - fi;
        float w4_0 = wfar(1.0f + t);   // tap i0-1
        float w4_1 = wnear(t);         // tap i0
        float w4_2 = wnear(1.0f - t);  // tap i0+1
        float w4_3 = wfar(2.0f - t);   // tap i0+2 (=0 when t==0)
        int off = i0 - i0min;          // 0 or 1
        float w4[4] = {w4_0, w4_1, w4_2, w4_3};
#pragma unroll
        for (int m = 0; m < 5; ++m) {
            float c0 = (m < 4) ? w4[m] : 0.0f;       // off==0: tap s+m = i0-1+m
            float c1 = (m >= 1) ? w4[m - 1] : 0.0f;  // off==1
            acc[m] += b * ((off == 0) ? c0 : c1);
        }
    }
#pragma unroll
    for (int m = 0; m < 5; ++m) w[m] = acc[m];
    *s_out = s;
}

__global__ __launch_bounds__(256) void bsw_kernel(
    const float* __restrict__ coords,  // [16,1024,1024,2]
    const float* __restrict__ disp,    // [16,2,32,32]
    float* __restrict__ out)           // [16,1024,1024,2]
{
    __shared__ __align__(16) float Dl[2][32][32];  // 8 KB control-point image
    __shared__ float wyl[32][5];
    __shared__ int   syl[32];

    const int b   = blockIdx.x;
    const int n   = b >> 7;        // 128 blocks per image
    const int r   = b & 127;
    const int ty  = r >> 2;        // 32 y-tiles
    const int tx  = r & 3;         // 4 x-tiles
    const int y0  = ty << 5;       // 32 rows
    const int x0  = tx << 8;       // 256 cols
    const int tid = threadIdx.x;

    // Stage displacements for image n: 2048 floats = 512 float4.
    {
        const float4* dsrc = (const float4*)(disp + (size_t)n * 2048);
        float4* ddst = (float4*)(&Dl[0][0][0]);
        ddst[tid]       = dsrc[tid];
        ddst[tid + 256] = dsrc[tid + 256];
    }

    // Per-row y weights (32 rows) into LDS.
    if (tid < 32) {
        float w[5]; int s;
        combined_weights(y0 + tid, w, &s);
#pragma unroll
        for (int m = 0; m < 5; ++m) wyl[tid][m] = w[m];
        syl[tid] = s;
    }

    // Own-column x weights in registers.
    const int x = x0 + tid;
    float wx[5]; int sx;
    combined_weights(x, wx, &sx);
    int cx[5];
#pragma unroll
    for (int j = 0; j < 5; ++j) cx[j] = min(max(sx + j, 0), 31);

    __syncthreads();

    const int s0 = syl[0];  // min base over tile (monotone in y); tile union = s0..s0+5

    // x-filtered coarse rows, both channels, in registers.
    float T0[6], T1[6];
#pragma unroll
    for (int k = 0; k < 6; ++k) {
        int rk = min(max(s0 + k, 0), 31);
        float a0 = 0.f, a1 = 0.f;
#pragma unroll
        for (int j = 0; j < 5; ++j) {
            a0 += wx[j] * Dl[0][rk][cx[j]];
            a1 += wx[j] * Dl[1][rk][cx[j]];
        }
        T0[k] = a0; T1[k] = a1;
    }

    const size_t base = ((size_t)n << 20) + ((size_t)y0 << 10) + (size_t)x;
    const float2* cp = (const float2*)coords + base;
    float2* op = (float2*)out + base;

#pragma unroll 4
    for (int yi = 0; yi < 32; ++yi) {
        const int shift = syl[yi] - s0;  // 0 or 1
        float wy[5];
#pragma unroll
        for (int m = 0; m < 5; ++m) wy[m] = wyl[yi][m];
        float w6[6];
#pragma unroll
        for (int k = 0; k < 6; ++k) {
            float a0 = (k < 5) ? wy[k] : 0.0f;
            float a1 = (k >= 1) ? wy[k - 1] : 0.0f;
            w6[k] = (shift == 0) ? a0 : a1;
        }
        float d0 = 0.f, d1 = 0.f;
#pragma unroll
        for (int k = 0; k < 6; ++k) {
            d0 += w6[k] * T0[k];
            d1 += w6[k] * T1[k];
        }
        float2 c = cp[(size_t)yi << 10];
        float2 o;
        o.x = c.x + d0;
        o.y = c.y + d1;
        op[(size_t)yi << 10] = o;
    }
}

extern "C" void kernel_launch(void* const* d_in, const int* in_sizes, int n_in,
                              void* d_out, int out_size, void* d_ws, size_t ws_size,
                              hipStream_t stream) {
    const float* coords = (const float*)d_in[0];  // [16,1024,1024,2]
    const float* disp   = (const float*)d_in[1];  // [16,2,32,32]
    float* out = (float*)d_out;

    // 16 images * (32 y-tiles) * (4 x-tiles) = 2048 blocks
    bsw_kernel<<<2048, 256, 0, stream>>>(coords, disp, out);
}

// Round 4
// 46.732 us; speedup vs baseline: 1.0839x; 1.0839x over previous
//
#include <hip/hip_runtime.h>

// BSplineWarp: out[n,y,x,c] = coords[n,y,x,c] + deltas[n,c,y,x]
// deltas = 3-tap blur([1/6,4/6,1/6], replicate) o bicubic_upsample(32->1024) of disp.
// Combined per-axis filter: <=5 taps on the 32-point coarse grid.

typedef float f32x4 __attribute__((ext_vector_type(4)));

#define A_COEF (-0.75f)

__device__ __forceinline__ float wnear(float d) {
    return ((A_COEF + 2.0f) * d - (A_COEF + 3.0f)) * d * d + 1.0f;
}
__device__ __forceinline__ float wfar(float d) {
    return A_COEF * (((d - 5.0f) * d + 8.0f) * d - 4.0f);
}

// Combined blur+bicubic weights for output coordinate q in [0,1024), in-size 32.
// Produces w[0..4] for (unclamped) coarse taps s..s+4; reader clamps tap to [0,31].
__device__ __forceinline__ void combined_weights(int q, float* w, int* s_out) {
    float acc[5] = {0.f, 0.f, 0.f, 0.f, 0.f};
    const float inv32 = 1.0f / 32.0f;

    int ym = max(q - 1, 0);
    float posm = ((float)ym + 0.5f) * inv32 - 0.5f;
    int i0min = (int)floorf(posm);
    int s = i0min - 1;

#pragma unroll
    for (int dy = -1; dy <= 1; ++dy) {
        float b = (dy == 0) ? (2.0f / 3.0f) : (1.0f / 6.0f);
        int yp = min(max(q + dy, 0), 1023);
        float pos = ((float)yp + 0.5f) * inv32 - 0.5f;
        float fi = floorf(pos);
        int i0 = (int)fi;
        float t = pos - fi;
        float w4_0 = wfar(1.0f + t);   // tap i0-1
        float w4_1 = wnear(t);         // tap i0
        float w4_2 = wnear(1.0f - t);  // tap i0+1
        float w4_3 = wfar(2.0f - t);   // tap i0+2 (=0 when t==0)
        int off = i0 - i0min;          // 0 or 1
        float w4[4] = {w4_0, w4_1, w4_2, w4_3};
#pragma unroll
        for (int m = 0; m < 5; ++m) {
            float c0 = (m < 4) ? w4[m] : 0.0f;       // off==0: tap s+m = i0-1+m
            float c1 = (m >= 1) ? w4[m - 1] : 0.0f;  // off==1
            acc[m] += b * ((off == 0) ? c0 : c1);
        }
    }
#pragma unroll
    for (int m = 0; m < 5; ++m) w[m] = acc[m];
    *s_out = s;
}

__global__ __launch_bounds__(256) void bsw_kernel(
    const float* __restrict__ coords,  // [16,1024,1024,2]
    const float* __restrict__ disp,    // [16,2,32,32]
    float* __restrict__ out)           // [16,1024,1024,2]
{
    __shared__ __align__(16) float Dl[2][32][32];  // 8 KB control-point image
    __shared__ float wyl[16][5];
    __shared__ int   syl[16];

    const int b   = blockIdx.x;
    const int n   = b >> 7;        // 128 blocks per image
    const int r   = b & 127;
    const int ty  = r >> 1;        // 64 y-tiles of 16 rows
    const int tx  = r & 1;         // 2 x-tiles of 512 cols
    const int y0  = ty << 4;
    const int x0  = tx << 9;
    const int tid = threadIdx.x;

    // Stage displacements for image n: 2048 floats = 512 float4.
    {
        const f32x4* dsrc = (const f32x4*)(disp + (size_t)n * 2048);
        f32x4* ddst = (f32x4*)(&Dl[0][0][0]);
        ddst[tid]       = dsrc[tid];
        ddst[tid + 256] = dsrc[tid + 256];
    }

    // Per-row y weights (16 rows) into LDS.
    if (tid < 16) {
        float w[5]; int s;
        combined_weights(y0 + tid, w, &s);
#pragma unroll
        for (int m = 0; m < 5; ++m) wyl[tid][m] = w[m];
        syl[tid] = s;
    }

    // Two adjacent pixels per thread: xa = x0 + 2*tid, xb = xa+1.
    const int xa = x0 + (tid << 1);
    float wxa[5], wxb[5]; int sxa, sxb;
    combined_weights(xa, wxa, &sxa);
    combined_weights(xa + 1, wxb, &sxb);
    int cxa[5], cxb[5];
#pragma unroll
    for (int j = 0; j < 5; ++j) {
        cxa[j] = min(max(sxa + j, 0), 31);
        cxb[j] = min(max(sxb + j, 0), 31);
    }

    __syncthreads();

    const int s0 = syl[0];  // min y-base over tile (monotone); tile union = s0..s0+5

    // x-filtered coarse rows, both channels, both pixels, in registers.
    float Ta0[6], Ta1[6], Tb0[6], Tb1[6];
#pragma unroll
    for (int k = 0; k < 6; ++k) {
        int rk = min(max(s0 + k, 0), 31);
        float a0 = 0.f, a1 = 0.f, b0 = 0.f, b1 = 0.f;
#pragma unroll
        for (int j = 0; j < 5; ++j) {
            a0 += wxa[j] * Dl[0][rk][cxa[j]];
            a1 += wxa[j] * Dl[1][rk][cxa[j]];
            b0 += wxb[j] * Dl[0][rk][cxb[j]];
            b1 += wxb[j] * Dl[1][rk][cxb[j]];
        }
        Ta0[k] = a0; Ta1[k] = a1; Tb0[k] = b0; Tb1[k] = b1;
    }

    // f32x4 = 2 pixels (x,y interleaved channels). Row = 512 f32x4.
    const size_t base4 = ((size_t)n << 19) + ((size_t)y0 << 9) + (size_t)(x0 >> 1) + (size_t)tid;
    const f32x4* cp = (const f32x4*)coords + base4;
    f32x4* op = (f32x4*)out + base4;

#pragma unroll 4
    for (int yi = 0; yi < 16; ++yi) {
        const int shift = syl[yi] - s0;  // 0 or 1
        float wy[5];
#pragma unroll
        for (int m = 0; m < 5; ++m) wy[m] = wyl[yi][m];
        float w6[6];
#pragma unroll
        for (int k = 0; k < 6; ++k) {
            float a0 = (k < 5) ? wy[k] : 0.0f;
            float a1 = (k >= 1) ? wy[k - 1] : 0.0f;
            w6[k] = (shift == 0) ? a0 : a1;
        }
        float da0 = 0.f, da1 = 0.f, db0 = 0.f, db1 = 0.f;
#pragma unroll
        for (int k = 0; k < 6; ++k) {
            da0 += w6[k] * Ta0[k];
            da1 += w6[k] * Ta1[k];
            db0 += w6[k] * Tb0[k];
            db1 += w6[k] * Tb1[k];
        }
        f32x4 c = cp[(size_t)yi << 9];
        f32x4 o;
        o.x = c.x + da0;
        o.y = c.y + da1;
        o.z = c.z + db0;
        o.w = c.w + db1;
        __builtin_nontemporal_store(o, &op[(size_t)yi << 9]);
    }
}

extern "C" void kernel_launch(void* const* d_in, const int* in_sizes, int n_in,
                              void* d_out, int out_size, void* d_ws, size_t ws_size,
                              hipStream_t stream) {
    const float* coords = (const float*)d_in[0];  // [16,1024,1024,2]
    const float* disp   = (const float*)d_in[1];  // [16,2,32,32]
    float* out = (float*)d_out;

    // 16 images * (64 y-tiles) * (2 x-tiles) = 2048 blocks
    bsw_kernel<<<2048, 256, 0, stream>>>(coords, disp, out);
}